// Round 4
// baseline (54.209 us; speedup 1.0000x reference)
//
#include <hip/hip_runtime.h>

// BasisVQ: quantized[b,k,:] = basis[argmax_c latent[b,k,c], :]
//          indices[b,k]     = argmax_c latent[b,k,c]
// B=16, K=2048, C=1024, D=900. Output = [quantized (B*K*D f32), indices (B*K as f32)].
//
// R4: fused (R3 split regressed), 2 rows per wave with all latent loads issued
// up front -> in-wave software pipeline: row1's loads are in flight while row0
// is reduced/gathered/stored. <=64 VGPR target keeps 8 waves/SIMD.

#define C_DIM 1024
#define D_DIM 900
#define ROWS_PER_WAVE 2

typedef float vfloat4 __attribute__((ext_vector_type(4)));

__device__ __forceinline__ int wave_argmax(vfloat4 v0, vfloat4 v1, vfloat4 v2,
                                           vfloat4 v3, int lane) {
    // per-lane argmax over 16 elems, first-index-wins (ascending, strict >)
    float m = v0[0];
    int   mi = lane * 4;
    #pragma unroll
    for (int e = 1; e < 4; ++e)
        if (v0[e] > m) { m = v0[e]; mi = lane * 4 + e; }
    #pragma unroll
    for (int e = 0; e < 4; ++e)
        if (v1[e] > m) { m = v1[e]; mi = (64 + lane) * 4 + e; }
    #pragma unroll
    for (int e = 0; e < 4; ++e)
        if (v2[e] > m) { m = v2[e]; mi = (128 + lane) * 4 + e; }
    #pragma unroll
    for (int e = 0; e < 4; ++e)
        if (v3[e] > m) { m = v3[e]; mi = (192 + lane) * 4 + e; }

    // wave(64) butterfly argmax, tie -> lowest index (matches jnp.argmax)
    #pragma unroll
    for (int off = 32; off > 0; off >>= 1) {
        float om = __shfl_xor(m, off, 64);
        int   oi = __shfl_xor(mi, off, 64);
        if (om > m || (om == m && oi < mi)) { m = om; mi = oi; }
    }
    return mi;
}

__device__ __forceinline__ void gather_store(const float* __restrict__ basis,
                                             float* __restrict__ out_q,
                                             int idx, size_t row, int lane) {
    const vfloat4* b4 = reinterpret_cast<const vfloat4*>(basis + (size_t)idx * D_DIM);
    vfloat4*       o4 = reinterpret_cast<vfloat4*>(out_q + row * D_DIM);
    #pragma unroll
    for (int j = 0; j < 4; ++j) {
        int t = 64 * j + lane;
        if (t < 225) {
            vfloat4 bv = b4[t];                       // cacheable: basis stays in L2
            __builtin_nontemporal_store(bv, &o4[t]);  // stream out
        }
    }
}

__global__ __launch_bounds__(256) void basisvq_kernel(
    const float* __restrict__ latent,   // [ROWS, 1024]
    const float* __restrict__ basis,    // [1024, 900]
    float* __restrict__ out_q,          // [ROWS, 900]
    float* __restrict__ out_idx,        // [ROWS]
    int rows)
{
    const int lane = threadIdx.x & 63;
    const int wv   = blockIdx.x * 4 + (threadIdx.x >> 6);   // global wave id
    const int r0   = wv * ROWS_PER_WAVE;
    if (r0 >= rows) return;

    // ---- issue ALL latent loads for both rows up front (8 in flight) ----
    const vfloat4* l0 = reinterpret_cast<const vfloat4*>(latent + (size_t)r0 * C_DIM);
    vfloat4 a0 = __builtin_nontemporal_load(&l0[lane]);
    vfloat4 a1 = __builtin_nontemporal_load(&l0[lane + 64]);
    vfloat4 a2 = __builtin_nontemporal_load(&l0[lane + 128]);
    vfloat4 a3 = __builtin_nontemporal_load(&l0[lane + 192]);

    const vfloat4* l1 = reinterpret_cast<const vfloat4*>(latent + (size_t)(r0 + 1) * C_DIM);
    vfloat4 b0 = __builtin_nontemporal_load(&l1[lane]);
    vfloat4 b1 = __builtin_nontemporal_load(&l1[lane + 64]);
    vfloat4 b2 = __builtin_nontemporal_load(&l1[lane + 128]);
    vfloat4 b3 = __builtin_nontemporal_load(&l1[lane + 192]);

    // ---- row 0: reduce, write idx, gather+store (row1 loads still in flight) ----
    int idx0 = wave_argmax(a0, a1, a2, a3, lane);
    if (lane == 0) __builtin_nontemporal_store((float)idx0, &out_idx[r0]);
    gather_store(basis, out_q, idx0, (size_t)r0, lane);

    // ---- row 1 ----
    int idx1 = wave_argmax(b0, b1, b2, b3, lane);
    if (lane == 0) __builtin_nontemporal_store((float)idx1, &out_idx[r0 + 1]);
    gather_store(basis, out_q, idx1, (size_t)(r0 + 1), lane);
}

extern "C" void kernel_launch(void* const* d_in, const int* in_sizes, int n_in,
                              void* d_out, int out_size, void* d_ws, size_t ws_size,
                              hipStream_t stream) {
    const float* latent = (const float*)d_in[0];   // 16*2048*1024
    const float* basis  = (const float*)d_in[1];   // 1024*900
    (void)n_in; (void)d_ws; (void)ws_size; (void)out_size;

    const int rows = in_sizes[0] / C_DIM;          // 32768
    float* out_q   = (float*)d_out;                // rows*900
    float* out_idx = (float*)d_out + (size_t)rows * D_DIM;

    // 4 waves/block, 2 rows/wave -> 8 rows per block
    const int blocks = (rows + 8 - 1) / 8;         // 4096
    basisvq_kernel<<<blocks, 256, 0, stream>>>(latent, basis, out_q, out_idx, rows);
}